// Round 7
// baseline (371.035 us; speedup 1.0000x reference)
//
#include <hip/hip_runtime.h>

#define N_VOX 100000
#define K_OFF 27
#define M_PAIR 60000
#define NPAIR (K_OFF * M_PAIR)
#define CIN 64
#define COUT 64
#define BN_EPS 1e-5f

typedef __attribute__((ext_vector_type(8))) short bf16x8;
typedef __attribute__((ext_vector_type(8))) unsigned short u16x8;
typedef __attribute__((ext_vector_type(4))) float f32x4;

__device__ __forceinline__ unsigned short f32_to_bf16(float f) {
    unsigned int u = __float_as_uint(f);
    u += 0x7FFFu + ((u >> 16) & 1u);
    return (unsigned short)(u >> 16);
}
__device__ __forceinline__ float bf16_to_f32(unsigned short b) {
    return __uint_as_float(((unsigned int)b) << 16);
}

// ---------- prep ----------

__global__ __launch_bounds__(256) void prep_feats_kernel(
    const float* __restrict__ feats, unsigned short* __restrict__ fb,
    float* __restrict__ out, int zero_out)
{
    const int e4 = (blockIdx.x * blockDim.x + threadIdx.x) * 4;
    if (e4 >= N_VOX * CIN) return;
    const float4 v = *(const float4*)(feats + e4);
    ushort4 b;
    b.x = f32_to_bf16(v.x);
    b.y = f32_to_bf16(v.y);
    b.z = f32_to_bf16(v.z);
    b.w = f32_to_bf16(v.w);
    *(ushort4*)(fb + e4) = b;
    if (zero_out) *(float4*)(out + e4) = make_float4(0.f, 0.f, 0.f, 0.f);
}

// W[k][i][c] fp32 -> Wt[k][c][i] bf16.
__global__ __launch_bounds__(256) void prep_w_kernel(
    const float* __restrict__ W, unsigned short* __restrict__ Wt)
{
    const int e = blockIdx.x * blockDim.x + threadIdx.x;
    if (e >= K_OFF * CIN * COUT) return;
    const int k = e / (CIN * COUT);
    const int r = e % (CIN * COUT);
    const int i = r / COUT;
    const int c = r % COUT;
    Wt[k * CIN * COUT + c * CIN + i] = f32_to_bf16(W[e]);
}

// ---------- CSR build: hist -> per-block alloc -> pos (coalesced) ----------

__global__ __launch_bounds__(256) void hist_kernel(
    const int* __restrict__ oix, int* __restrict__ cnt)
{
    const int e = blockIdx.x * blockDim.x + threadIdx.x;
    if (e < NPAIR) atomicAdd(&cnt[oix[e]], 1);
}

// Per-block LDS scan + one global allocator atomic per block (391 total).
__global__ __launch_bounds__(256) void alloc_kernel(
    const int* __restrict__ cnt, int* __restrict__ total,
    int* __restrict__ seg, int* __restrict__ cursor)
{
    __shared__ int part[256];
    __shared__ int bbase;
    const int t = threadIdx.x;
    const int v = blockIdx.x * 256 + t;
    const int c = (v < N_VOX) ? cnt[v] : 0;
    part[t] = c;
    __syncthreads();
    for (int o = 1; o < 256; o <<= 1) {
        int x = (t >= o) ? part[t - o] : 0;
        __syncthreads();
        part[t] += x;
        __syncthreads();
    }
    if (t == 255) bbase = atomicAdd(total, part[255]);
    __syncthreads();
    if (v < N_VOX) {
        const int excl = part[t] - c;
        seg[v] = bbase + excl;
        cursor[v] = bbase + excl;
    }
}

// pos[e] = sorted slot of pair e (written coalesced).
__global__ __launch_bounds__(256) void pos_kernel(
    const int* __restrict__ oix, int* __restrict__ cursor, int* __restrict__ pos)
{
    const int e = blockIdx.x * blockDim.x + threadIdx.x;
    if (e < NPAIR) pos[e] = atomicAdd(&cursor[oix[e]], 1);
}

// ---------- phase A: gather-GEMM, write rows to sorted slots ----------
// 250 waves per k, 15 tiles each (grid doubled vs r6 for occupancy).
// Wave-private LDS slab -> no __syncthreads; full-line 128B row stores.
__global__ __launch_bounds__(256) void conv_scatter_kernel(
    const unsigned short* __restrict__ fb, const unsigned short* __restrict__ Wt,
    const int* __restrict__ in_idx, const int* __restrict__ pos_of_pair,
    unsigned short* __restrict__ contrib)
{
    __shared__ alignas(16) unsigned short lds[4][16 * 72];
    const int k = blockIdx.y;
    const int lane = threadIdx.x & 63;
    const int wid = threadIdx.x >> 6;
    const int w = blockIdx.x * 4 + wid;
    if (w >= 250) return;
    const int col = lane & 15;
    const int quad = lane >> 4;
    unsigned short* L = lds[wid];

    bf16x8 Bf[4][2];
    const short* Wk = (const short*)(Wt + k * CIN * COUT);
#pragma unroll
    for (int t = 0; t < 4; ++t) {
        const short* p = Wk + (t * 16 + col) * CIN + quad * 8;
        Bf[t][0] = *(const bf16x8*)(p);
        Bf[t][1] = *(const bf16x8*)(p + 32);
    }

    const int base = k * M_PAIR;
    for (int it = 0; it < 15; ++it) {
        const int m0 = base + (w * 15 + it) * 16;

        const int rin = in_idx[m0 + col];
        const short* fp = (const short*)fb + (size_t)rin * CIN + quad * 8;
        const bf16x8 A0 = *(const bf16x8*)(fp);
        const bf16x8 A1 = *(const bf16x8*)(fp + 32);

        f32x4 acc[4];
#pragma unroll
        for (int t = 0; t < 4; ++t) {
            f32x4 z = {0.f, 0.f, 0.f, 0.f};
            acc[t] = __builtin_amdgcn_mfma_f32_16x16x32_bf16(A0, Bf[t][0], z, 0, 0, 0);
            acc[t] = __builtin_amdgcn_mfma_f32_16x16x32_bf16(A1, Bf[t][1], acc[t], 0, 0, 0);
        }

        // C/D layout (cout = t*16+col, row = quad*4+r) -> LDS [row][72].
#pragma unroll
        for (int r = 0; r < 4; ++r) {
            const int row = quad * 4 + r;
#pragma unroll
            for (int t = 0; t < 4; ++t)
                L[row * 72 + t * 16 + col] = f32_to_bf16(acc[t][r]);
        }
        // Writeback: 8 lanes per 128B row; slot = pos_of_pair[pair].
#pragma unroll
        for (int itr = 0; itr < 2; ++itr) {
            const int row = itr * 8 + (lane >> 3);
            const int chunk = lane & 7;
            const int pos = pos_of_pair[m0 + row];
            const u16x8 v = *(const u16x8*)(L + row * 72 + chunk * 8);
            *(u16x8*)(contrib + (size_t)pos * 64 + chunk * 8) = v;
        }
    }
}

// ---------- phase B: streaming segmented sum + fused BN + ReLU ----------
// Lane-split wave: lanes 0-31 even rows, 32-63 odd rows; uint loads (2 ch);
// __shfl_xor(32) merges halves; lanes 0-31 store float2.
__global__ __launch_bounds__(256) void gather_bn_kernel(
    const unsigned short* __restrict__ contrib, const int* __restrict__ seg,
    const int* __restrict__ cnt,
    const float* __restrict__ gamma, const float* __restrict__ beta,
    const float* __restrict__ mean, const float* __restrict__ var,
    float* __restrict__ out)
{
    const int v = blockIdx.x * 4 + (threadIdx.x >> 6);   // one wave per voxel
    if (v >= N_VOX) return;
    const int lane = threadIdx.x & 63;
    const int half = lane >> 5;        // 0: even rows, 1: odd rows
    const int l = lane & 31;           // uint index (channels 2l, 2l+1)
    const int s = seg[v];
    const int n = cnt[v];

    const unsigned int* p = (const unsigned int*)(contrib + (size_t)s * 64) + l;
    float c0 = 0.f, c1 = 0.f, d0 = 0.f, d1 = 0.f;
    int j = half;
    for (; j + 2 < n; j += 4) {
        const unsigned int u0 = p[(size_t)j * 32];
        const unsigned int u1 = p[(size_t)(j + 2) * 32];
        c0 += bf16_to_f32((unsigned short)u0);
        c1 += bf16_to_f32((unsigned short)(u0 >> 16));
        d0 += bf16_to_f32((unsigned short)u1);
        d1 += bf16_to_f32((unsigned short)(u1 >> 16));
    }
    if (j < n) {
        const unsigned int u0 = p[(size_t)j * 32];
        c0 += bf16_to_f32((unsigned short)u0);
        c1 += bf16_to_f32((unsigned short)(u0 >> 16));
    }
    c0 += d0;
    c1 += d1;
    c0 += __shfl_xor(c0, 32, 64);
    c1 += __shfl_xor(c1, 32, 64);
    if (half == 0) {
        const int ch = 2 * l;
        const float inv0 = rsqrtf(var[ch] + BN_EPS);
        const float inv1 = rsqrtf(var[ch + 1] + BN_EPS);
        const float y0 = (c0 - mean[ch]) * (inv0 * gamma[ch]) + beta[ch];
        const float y1 = (c1 - mean[ch + 1]) * (inv1 * gamma[ch + 1]) + beta[ch + 1];
        float2 r;
        r.x = fmaxf(y0, 0.f);
        r.y = fmaxf(y1, 0.f);
        *(float2*)(out + (size_t)v * 64 + ch) = r;
    }
}

// ---------- fallback (atomic path, used if ws too small) ----------
__global__ __launch_bounds__(256) void conv_atomic_kernel(
    const unsigned short* __restrict__ fb, const unsigned short* __restrict__ Wt,
    const int* __restrict__ in_idx, const int* __restrict__ out_idx,
    float* __restrict__ out)
{
    const int k = blockIdx.y;
    const int lane = threadIdx.x & 63;
    const int wave = blockIdx.x * 4 + (threadIdx.x >> 6);
    const int col = lane & 15;
    const int quad = lane >> 4;
    bf16x8 Bf[4][2];
    const short* Wk = (const short*)(Wt + k * CIN * COUT);
#pragma unroll
    for (int t = 0; t < 4; ++t) {
        const short* p = Wk + (t * 16 + col) * CIN + quad * 8;
        Bf[t][0] = *(const bf16x8*)(p);
        Bf[t][1] = *(const bf16x8*)(p + 32);
    }
    const int base = k * M_PAIR;
    for (int tile = wave; tile < M_PAIR / 16; tile += 128) {
        const int m0 = base + tile * 16;
        const int rin = in_idx[m0 + col];
        const short* fp = (const short*)fb + (size_t)rin * CIN + quad * 8;
        const bf16x8 A0 = *(const bf16x8*)(fp);
        const bf16x8 A1 = *(const bf16x8*)(fp + 32);
        f32x4 acc[4];
#pragma unroll
        for (int t = 0; t < 4; ++t) {
            f32x4 z = {0.f, 0.f, 0.f, 0.f};
            acc[t] = __builtin_amdgcn_mfma_f32_16x16x32_bf16(A0, Bf[t][0], z, 0, 0, 0);
            acc[t] = __builtin_amdgcn_mfma_f32_16x16x32_bf16(A1, Bf[t][1], acc[t], 0, 0, 0);
        }
        int vo[4];
#pragma unroll
        for (int r = 0; r < 4; ++r) vo[r] = out_idx[m0 + quad * 4 + r];
#pragma unroll
        for (int r = 0; r < 4; ++r) {
            float* op = out + (size_t)vo[r] * COUT + col;
#pragma unroll
            for (int t = 0; t < 4; ++t) atomicAdd(op + t * 16, acc[t][r]);
        }
    }
}

__global__ __launch_bounds__(256) void bn_relu_kernel(
    float* __restrict__ out,
    const float* __restrict__ gamma, const float* __restrict__ beta,
    const float* __restrict__ mean, const float* __restrict__ var)
{
    const int e = blockIdx.x * blockDim.x + threadIdx.x;
    if (e >= N_VOX * COUT) return;
    const int c = e & (COUT - 1);
    const float inv = rsqrtf(var[c] + BN_EPS);
    const float y = (out[e] - mean[c]) * (inv * gamma[c]) + beta[c];
    out[e] = fmaxf(y, 0.f);
}

// ---------- host ----------
extern "C" void kernel_launch(void* const* d_in, const int* in_sizes, int n_in,
                              void* d_out, int out_size, void* d_ws, size_t ws_size,
                              hipStream_t stream) {
    const float* feats = (const float*)d_in[0];
    const float* W     = (const float*)d_in[1];
    const float* gamma = (const float*)d_in[2];
    const float* beta  = (const float*)d_in[3];
    const float* rmean = (const float*)d_in[4];
    const float* rvar  = (const float*)d_in[5];
    const int* in_idx  = (const int*)d_in[6];
    const int* out_idx = (const int*)d_in[7];
    float* out = (float*)d_out;

    char* ws = (char*)d_ws;
    size_t off = 0;
    auto alloc = [&](size_t bytes) {
        size_t p = off;
        off = (off + bytes + 255) & ~(size_t)255;
        return p;
    };
    const size_t o_fb   = alloc((size_t)N_VOX * CIN * 2);
    const size_t o_wt   = alloc((size_t)K_OFF * CIN * COUT * 2);
    const size_t o_cnt  = alloc((size_t)N_VOX * 4);
    const size_t o_tot  = alloc(4);
    const size_t o_seg  = alloc((size_t)N_VOX * 4);
    const size_t o_cur  = alloc((size_t)N_VOX * 4);
    const size_t o_pos  = alloc((size_t)NPAIR * 4);
    const size_t o_ctr  = alloc((size_t)NPAIR * COUT * 2);
    const bool big = (ws_size >= off);       // constant across calls -> graph-safe

    unsigned short* fb  = (unsigned short*)(ws + o_fb);
    unsigned short* Wt  = (unsigned short*)(ws + o_wt);
    int* cnt            = (int*)(ws + o_cnt);
    int* total          = (int*)(ws + o_tot);
    int* seg            = (int*)(ws + o_seg);
    int* cursor         = (int*)(ws + o_cur);
    int* pos            = (int*)(ws + o_pos);
    unsigned short* ctr = (unsigned short*)(ws + o_ctr);

    const int n_vec4 = (N_VOX * CIN) / 4;
    prep_feats_kernel<<<(n_vec4 + 255) / 256, 256, 0, stream>>>(feats, fb, out, big ? 0 : 1);
    const int wtot = K_OFF * CIN * COUT;
    prep_w_kernel<<<(wtot + 255) / 256, 256, 0, stream>>>(W, Wt);

    if (big) {
        hipMemsetAsync(cnt, 0, (size_t)N_VOX * 4, stream);
        hipMemsetAsync(total, 0, 4, stream);
        hist_kernel<<<(NPAIR + 255) / 256, 256, 0, stream>>>(out_idx, cnt);
        alloc_kernel<<<(N_VOX + 255) / 256, 256, 0, stream>>>(cnt, total, seg, cursor);
        pos_kernel<<<(NPAIR + 255) / 256, 256, 0, stream>>>(out_idx, cursor, pos);
        conv_scatter_kernel<<<dim3(64, K_OFF), 256, 0, stream>>>(fb, Wt, in_idx, pos, ctr);
        gather_bn_kernel<<<(N_VOX + 3) / 4, 256, 0, stream>>>(ctr, seg, cnt,
                                                              gamma, beta, rmean, rvar, out);
    } else {
        conv_atomic_kernel<<<dim3(32, K_OFF), 256, 0, stream>>>(fb, Wt, in_idx, out_idx, out);
        const int total_e = N_VOX * COUT;
        bn_relu_kernel<<<(total_e + 255) / 256, 256, 0, stream>>>(out, gamma, beta, rmean, rvar);
    }
}

// Round 8
// 316.840 us; speedup vs baseline: 1.1710x; 1.1710x over previous
//
#include <hip/hip_runtime.h>

#define N_VOX 100000
#define K_OFF 27
#define M_PAIR 60000
#define NPAIR (K_OFF * M_PAIR)
#define CIN 64
#define COUT 64
#define BN_EPS 1e-5f

typedef __attribute__((ext_vector_type(8))) short bf16x8;
typedef __attribute__((ext_vector_type(8))) unsigned short u16x8;
typedef __attribute__((ext_vector_type(4))) float f32x4;

__device__ __forceinline__ unsigned short f32_to_bf16(float f) {
    unsigned int u = __float_as_uint(f);
    u += 0x7FFFu + ((u >> 16) & 1u);
    return (unsigned short)(u >> 16);
}
__device__ __forceinline__ float bf16_to_f32(unsigned short b) {
    return __uint_as_float(((unsigned int)b) << 16);
}

// ---------- fused prep: hist atomic + feats->bf16 + W transpose ----------
// One dispatch over NPAIR threads; low-id threads also do the (smaller)
// conversion jobs. Saves 2 launches and overlaps streaming with atomics.
__global__ __launch_bounds__(256) void prep_hist_kernel(
    const int* __restrict__ oix, int* __restrict__ cnt,
    const float* __restrict__ feats, unsigned short* __restrict__ fb,
    const float* __restrict__ W, unsigned short* __restrict__ Wt)
{
    const int e = blockIdx.x * blockDim.x + threadIdx.x;
    if (e < NPAIR) atomicAdd(&cnt[oix[e]], 1);
    if (e < (N_VOX * CIN) / 4) {
        const int e4 = e * 4;
        const float4 v = *(const float4*)(feats + e4);
        ushort4 b;
        b.x = f32_to_bf16(v.x);
        b.y = f32_to_bf16(v.y);
        b.z = f32_to_bf16(v.z);
        b.w = f32_to_bf16(v.w);
        *(ushort4*)(fb + e4) = b;
    }
    if (e < K_OFF * CIN * COUT) {
        const int k = e / (CIN * COUT);
        const int r = e % (CIN * COUT);
        const int i = r / COUT;
        const int c = r % COUT;
        Wt[k * CIN * COUT + c * CIN + i] = f32_to_bf16(W[e]);
    }
}

// ---------- per-block alloc: LDS scan + one global allocator atomic ----------
__global__ __launch_bounds__(256) void alloc_kernel(
    const int* __restrict__ cnt, int* __restrict__ total,
    int* __restrict__ seg, int* __restrict__ cursor)
{
    __shared__ int part[256];
    __shared__ int bbase;
    const int t = threadIdx.x;
    const int v = blockIdx.x * 256 + t;
    const int c = (v < N_VOX) ? cnt[v] : 0;
    part[t] = c;
    __syncthreads();
    for (int o = 1; o < 256; o <<= 1) {
        int x = (t >= o) ? part[t - o] : 0;
        __syncthreads();
        part[t] += x;
        __syncthreads();
    }
    if (t == 255) bbase = atomicAdd(total, part[255]);
    __syncthreads();
    if (v < N_VOX) {
        const int excl = part[t] - c;
        seg[v] = bbase + excl;
        cursor[v] = bbase + excl;
    }
}

// ---------- phase A: gather-GEMM + inline slot claim + sorted-slot store ----
// 125 waves per k, 30 tiles each (round-6 grid: measured best). Wave-private
// LDS slab, no __syncthreads. Slot claimed at store time: lanes 0-15 do
// atomicAdd on cursor[out_idx], broadcast via __shfl -> pos_kernel deleted.
__global__ __launch_bounds__(256) void conv_scatter_kernel(
    const unsigned short* __restrict__ fb, const unsigned short* __restrict__ Wt,
    const int* __restrict__ in_idx, const int* __restrict__ out_idx,
    int* __restrict__ cursor, unsigned short* __restrict__ contrib)
{
    __shared__ alignas(16) unsigned short lds[4][16 * 72];
    const int k = blockIdx.y;
    const int lane = threadIdx.x & 63;
    const int wid = threadIdx.x >> 6;
    const int w = blockIdx.x * 4 + wid;
    if (w >= 125) return;
    const int col = lane & 15;
    const int quad = lane >> 4;
    unsigned short* L = lds[wid];

    bf16x8 Bf[4][2];
    const short* Wk = (const short*)(Wt + k * CIN * COUT);
#pragma unroll
    for (int t = 0; t < 4; ++t) {
        const short* p = Wk + (t * 16 + col) * CIN + quad * 8;
        Bf[t][0] = *(const bf16x8*)(p);
        Bf[t][1] = *(const bf16x8*)(p + 32);
    }

    const int base = k * M_PAIR;
    for (int it = 0; it < 30; ++it) {
        const int m0 = base + (w * 30 + it) * 16;

        // Claim sorted slots early so the atomic latency overlaps the MFMA
        // + LDS roundtrip below.
        int slot = 0;
        if (lane < 16) slot = atomicAdd(&cursor[out_idx[m0 + lane]], 1);

        const int rin = in_idx[m0 + col];
        const short* fp = (const short*)fb + (size_t)rin * CIN + quad * 8;
        const bf16x8 A0 = *(const bf16x8*)(fp);
        const bf16x8 A1 = *(const bf16x8*)(fp + 32);

        f32x4 acc[4];
#pragma unroll
        for (int t = 0; t < 4; ++t) {
            f32x4 z = {0.f, 0.f, 0.f, 0.f};
            acc[t] = __builtin_amdgcn_mfma_f32_16x16x32_bf16(A0, Bf[t][0], z, 0, 0, 0);
            acc[t] = __builtin_amdgcn_mfma_f32_16x16x32_bf16(A1, Bf[t][1], acc[t], 0, 0, 0);
        }

        // C/D layout (cout = t*16+col, row = quad*4+r) -> LDS [row][72].
#pragma unroll
        for (int r = 0; r < 4; ++r) {
            const int row = quad * 4 + r;
#pragma unroll
            for (int t = 0; t < 4; ++t)
                L[row * 72 + t * 16 + col] = f32_to_bf16(acc[t][r]);
        }
        // Writeback: 8 lanes per 128B row; slot broadcast from claiming lane.
#pragma unroll
        for (int itr = 0; itr < 2; ++itr) {
            const int row = itr * 8 + (lane >> 3);
            const int chunk = lane & 7;
            const int pos = __shfl(slot, row, 64);
            const u16x8 v = *(const u16x8*)(L + row * 72 + chunk * 8);
            *(u16x8*)(contrib + (size_t)pos * 64 + chunk * 8) = v;
        }
    }
}

// ---------- phase B: streaming segmented sum + fused BN + ReLU ----------
__global__ __launch_bounds__(256) void gather_bn_kernel(
    const unsigned short* __restrict__ contrib, const int* __restrict__ seg,
    const int* __restrict__ cnt,
    const float* __restrict__ gamma, const float* __restrict__ beta,
    const float* __restrict__ mean, const float* __restrict__ var,
    float* __restrict__ out)
{
    const int v = blockIdx.x * 4 + (threadIdx.x >> 6);   // one wave per voxel
    if (v >= N_VOX) return;
    const int lane = threadIdx.x & 63;
    const int half = lane >> 5;        // 0: even rows, 1: odd rows
    const int l = lane & 31;           // uint index (channels 2l, 2l+1)
    const int s = seg[v];
    const int n = cnt[v];

    const unsigned int* p = (const unsigned int*)(contrib + (size_t)s * 64) + l;
    float c0 = 0.f, c1 = 0.f, d0 = 0.f, d1 = 0.f;
    int j = half;
    for (; j + 2 < n; j += 4) {
        const unsigned int u0 = p[(size_t)j * 32];
        const unsigned int u1 = p[(size_t)(j + 2) * 32];
        c0 += bf16_to_f32((unsigned short)u0);
        c1 += bf16_to_f32((unsigned short)(u0 >> 16));
        d0 += bf16_to_f32((unsigned short)u1);
        d1 += bf16_to_f32((unsigned short)(u1 >> 16));
    }
    if (j < n) {
        const unsigned int u0 = p[(size_t)j * 32];
        c0 += bf16_to_f32((unsigned short)u0);
        c1 += bf16_to_f32((unsigned short)(u0 >> 16));
    }
    c0 += d0;
    c1 += d1;
    c0 += __shfl_xor(c0, 32, 64);
    c1 += __shfl_xor(c1, 32, 64);
    if (half == 0) {
        const int ch = 2 * l;
        const float inv0 = rsqrtf(var[ch] + BN_EPS);
        const float inv1 = rsqrtf(var[ch + 1] + BN_EPS);
        const float y0 = (c0 - mean[ch]) * (inv0 * gamma[ch]) + beta[ch];
        const float y1 = (c1 - mean[ch + 1]) * (inv1 * gamma[ch + 1]) + beta[ch + 1];
        float2 r;
        r.x = fmaxf(y0, 0.f);
        r.y = fmaxf(y1, 0.f);
        *(float2*)(out + (size_t)v * 64 + ch) = r;
    }
}

// ---------- fallback (atomic path, used if ws too small) ----------
__global__ __launch_bounds__(256) void prep_small_kernel(
    const float* __restrict__ feats, unsigned short* __restrict__ fb,
    float* __restrict__ out, const float* __restrict__ W,
    unsigned short* __restrict__ Wt)
{
    const int e = blockIdx.x * blockDim.x + threadIdx.x;
    if (e < (N_VOX * CIN) / 4) {
        const int e4 = e * 4;
        const float4 v = *(const float4*)(feats + e4);
        ushort4 b;
        b.x = f32_to_bf16(v.x);
        b.y = f32_to_bf16(v.y);
        b.z = f32_to_bf16(v.z);
        b.w = f32_to_bf16(v.w);
        *(ushort4*)(fb + e4) = b;
        *(float4*)(out + e4) = make_float4(0.f, 0.f, 0.f, 0.f);
    }
    if (e < K_OFF * CIN * COUT) {
        const int k = e / (CIN * COUT);
        const int r = e % (CIN * COUT);
        const int i = r / COUT;
        const int c = r % COUT;
        Wt[k * CIN * COUT + c * CIN + i] = f32_to_bf16(W[e]);
    }
}

__global__ __launch_bounds__(256) void conv_atomic_kernel(
    const unsigned short* __restrict__ fb, const unsigned short* __restrict__ Wt,
    const int* __restrict__ in_idx, const int* __restrict__ out_idx,
    float* __restrict__ out)
{
    const int k = blockIdx.y;
    const int lane = threadIdx.x & 63;
    const int wave = blockIdx.x * 4 + (threadIdx.x >> 6);
    const int col = lane & 15;
    const int quad = lane >> 4;
    bf16x8 Bf[4][2];
    const short* Wk = (const short*)(Wt + k * CIN * COUT);
#pragma unroll
    for (int t = 0; t < 4; ++t) {
        const short* p = Wk + (t * 16 + col) * CIN + quad * 8;
        Bf[t][0] = *(const bf16x8*)(p);
        Bf[t][1] = *(const bf16x8*)(p + 32);
    }
    const int base = k * M_PAIR;
    for (int tile = wave; tile < M_PAIR / 16; tile += 128) {
        const int m0 = base + tile * 16;
        const int rin = in_idx[m0 + col];
        const short* fp = (const short*)fb + (size_t)rin * CIN + quad * 8;
        const bf16x8 A0 = *(const bf16x8*)(fp);
        const bf16x8 A1 = *(const bf16x8*)(fp + 32);
        f32x4 acc[4];
#pragma unroll
        for (int t = 0; t < 4; ++t) {
            f32x4 z = {0.f, 0.f, 0.f, 0.f};
            acc[t] = __builtin_amdgcn_mfma_f32_16x16x32_bf16(A0, Bf[t][0], z, 0, 0, 0);
            acc[t] = __builtin_amdgcn_mfma_f32_16x16x32_bf16(A1, Bf[t][1], acc[t], 0, 0, 0);
        }
        int vo[4];
#pragma unroll
        for (int r = 0; r < 4; ++r) vo[r] = out_idx[m0 + quad * 4 + r];
#pragma unroll
        for (int r = 0; r < 4; ++r) {
            float* op = out + (size_t)vo[r] * COUT + col;
#pragma unroll
            for (int t = 0; t < 4; ++t) atomicAdd(op + t * 16, acc[t][r]);
        }
    }
}

__global__ __launch_bounds__(256) void bn_relu_kernel(
    float* __restrict__ out,
    const float* __restrict__ gamma, const float* __restrict__ beta,
    const float* __restrict__ mean, const float* __restrict__ var)
{
    const int e = blockIdx.x * blockDim.x + threadIdx.x;
    if (e >= N_VOX * COUT) return;
    const int c = e & (COUT - 1);
    const float inv = rsqrtf(var[c] + BN_EPS);
    const float y = (out[e] - mean[c]) * (inv * gamma[c]) + beta[c];
    out[e] = fmaxf(y, 0.f);
}

// ---------- host ----------
extern "C" void kernel_launch(void* const* d_in, const int* in_sizes, int n_in,
                              void* d_out, int out_size, void* d_ws, size_t ws_size,
                              hipStream_t stream) {
    const float* feats = (const float*)d_in[0];
    const float* W     = (const float*)d_in[1];
    const float* gamma = (const float*)d_in[2];
    const float* beta  = (const float*)d_in[3];
    const float* rmean = (const float*)d_in[4];
    const float* rvar  = (const float*)d_in[5];
    const int* in_idx  = (const int*)d_in[6];
    const int* out_idx = (const int*)d_in[7];
    float* out = (float*)d_out;

    char* ws = (char*)d_ws;
    size_t off = 0;
    auto alloc = [&](size_t bytes) {
        size_t p = off;
        off = (off + bytes + 255) & ~(size_t)255;
        return p;
    };
    const size_t o_fb   = alloc((size_t)N_VOX * CIN * 2);
    const size_t o_wt   = alloc((size_t)K_OFF * CIN * COUT * 2);
    const size_t o_cnt  = alloc((size_t)N_VOX * 4);
    const size_t o_tot  = alloc(4);
    const size_t o_seg  = alloc((size_t)N_VOX * 4);
    const size_t o_cur  = alloc((size_t)N_VOX * 4);
    const size_t o_ctr  = alloc((size_t)NPAIR * COUT * 2);
    const bool big = (ws_size >= off);       // constant across calls -> graph-safe

    unsigned short* fb  = (unsigned short*)(ws + o_fb);
    unsigned short* Wt  = (unsigned short*)(ws + o_wt);
    int* cnt            = (int*)(ws + o_cnt);
    int* total          = (int*)(ws + o_tot);
    int* seg            = (int*)(ws + o_seg);
    int* cursor         = (int*)(ws + o_cur);
    unsigned short* ctr = (unsigned short*)(ws + o_ctr);

    if (big) {
        hipMemsetAsync(cnt, 0, (size_t)N_VOX * 4, stream);
        hipMemsetAsync(total, 0, 4, stream);
        prep_hist_kernel<<<(NPAIR + 255) / 256, 256, 0, stream>>>(
            out_idx, cnt, feats, fb, W, Wt);
        alloc_kernel<<<(N_VOX + 255) / 256, 256, 0, stream>>>(cnt, total, seg, cursor);
        conv_scatter_kernel<<<dim3(32, K_OFF), 256, 0, stream>>>(
            fb, Wt, in_idx, out_idx, cursor, ctr);
        gather_bn_kernel<<<(N_VOX + 3) / 4, 256, 0, stream>>>(ctr, seg, cnt,
                                                              gamma, beta, rmean, rvar, out);
    } else {
        const int ptot = (N_VOX * CIN) / 4;
        prep_small_kernel<<<(ptot + 255) / 256, 256, 0, stream>>>(feats, fb, out, W, Wt);
        conv_atomic_kernel<<<dim3(32, K_OFF), 256, 0, stream>>>(fb, Wt, in_idx, out_idx, out);
        const int total_e = N_VOX * COUT;
        bn_relu_kernel<<<(total_e + 255) / 256, 256, 0, stream>>>(out, gamma, beta, rmean, rvar);
    }
}

// Round 9
// 294.060 us; speedup vs baseline: 1.2618x; 1.0775x over previous
//
#include <hip/hip_runtime.h>

#define N_VOX 100000
#define K_OFF 27
#define M_PAIR 60000
#define NPAIR (K_OFF * M_PAIR)
#define CIN 64
#define COUT 64
#define BN_EPS 1e-5f

typedef __attribute__((ext_vector_type(8))) short bf16x8;
typedef __attribute__((ext_vector_type(8))) unsigned short u16x8;
typedef __attribute__((ext_vector_type(4))) float f32x4;

__device__ __forceinline__ unsigned short f32_to_bf16(float f) {
    unsigned int u = __float_as_uint(f);
    u += 0x7FFFu + ((u >> 16) & 1u);
    return (unsigned short)(u >> 16);
}
__device__ __forceinline__ float bf16_to_f32(unsigned short b) {
    return __uint_as_float(((unsigned int)b) << 16);
}

// ---------- fused prep: hist atomic (rank saved!) + feats->bf16 + W^T ----------
// The hist atomic's return value IS the pair's rank within its voxel segment.
// Storing it (coalesced) lets conv compute its sorted slot with pure reads.
__global__ __launch_bounds__(256) void prep_rank_kernel(
    const int* __restrict__ oix, int* __restrict__ cnt, int* __restrict__ rank,
    const float* __restrict__ feats, unsigned short* __restrict__ fb,
    const float* __restrict__ W, unsigned short* __restrict__ Wt)
{
    const int e = blockIdx.x * blockDim.x + threadIdx.x;
    if (e < NPAIR) rank[e] = atomicAdd(&cnt[oix[e]], 1);
    if (e < (N_VOX * CIN) / 4) {
        const int e4 = e * 4;
        const float4 v = *(const float4*)(feats + e4);
        ushort4 b;
        b.x = f32_to_bf16(v.x);
        b.y = f32_to_bf16(v.y);
        b.z = f32_to_bf16(v.z);
        b.w = f32_to_bf16(v.w);
        *(ushort4*)(fb + e4) = b;
    }
    if (e < K_OFF * CIN * COUT) {
        const int k = e / (CIN * COUT);
        const int r = e % (CIN * COUT);
        const int i = r / COUT;
        const int c = r % COUT;
        Wt[k * CIN * COUT + c * CIN + i] = f32_to_bf16(W[e]);
    }
}

// ---------- per-block alloc: LDS scan + one global allocator atomic ----------
__global__ __launch_bounds__(256) void alloc_kernel(
    const int* __restrict__ cnt, int* __restrict__ total, int* __restrict__ seg)
{
    __shared__ int part[256];
    __shared__ int bbase;
    const int t = threadIdx.x;
    const int v = blockIdx.x * 256 + t;
    const int c = (v < N_VOX) ? cnt[v] : 0;
    part[t] = c;
    __syncthreads();
    for (int o = 1; o < 256; o <<= 1) {
        int x = (t >= o) ? part[t - o] : 0;
        __syncthreads();
        part[t] += x;
        __syncthreads();
    }
    if (t == 255) bbase = atomicAdd(total, part[255]);
    __syncthreads();
    if (v < N_VOX) seg[v] = bbase + (part[t] - c);
}

// ---------- phase A: gather-GEMM + pure-read slot + sorted-slot store ----------
// 125 waves per k, 30 tiles each. Wave-private LDS slab, no __syncthreads,
// ZERO atomics: slot = seg[out_idx[pair]] + rank[pair].
__global__ __launch_bounds__(256) void conv_scatter_kernel(
    const unsigned short* __restrict__ fb, const unsigned short* __restrict__ Wt,
    const int* __restrict__ in_idx, const int* __restrict__ out_idx,
    const int* __restrict__ rank, const int* __restrict__ seg,
    unsigned short* __restrict__ contrib)
{
    __shared__ alignas(16) unsigned short lds[4][16 * 72];
    const int k = blockIdx.y;
    const int lane = threadIdx.x & 63;
    const int wid = threadIdx.x >> 6;
    const int w = blockIdx.x * 4 + wid;
    if (w >= 125) return;
    const int col = lane & 15;
    const int quad = lane >> 4;
    unsigned short* L = lds[wid];

    bf16x8 Bf[4][2];
    const short* Wk = (const short*)(Wt + k * CIN * COUT);
#pragma unroll
    for (int t = 0; t < 4; ++t) {
        const short* p = Wk + (t * 16 + col) * CIN + quad * 8;
        Bf[t][0] = *(const bf16x8*)(p);
        Bf[t][1] = *(const bf16x8*)(p + 32);
    }

    const int base = k * M_PAIR;
    for (int it = 0; it < 30; ++it) {
        const int m0 = base + (w * 30 + it) * 16;

        // Slot computation: coalesced oix/rank loads + one random 4B seg read.
        int slot = 0;
        if (lane < 16)
            slot = seg[out_idx[m0 + lane]] + rank[m0 + lane];

        const int rin = in_idx[m0 + col];
        const short* fp = (const short*)fb + (size_t)rin * CIN + quad * 8;
        const bf16x8 A0 = *(const bf16x8*)(fp);
        const bf16x8 A1 = *(const bf16x8*)(fp + 32);

        f32x4 acc[4];
#pragma unroll
        for (int t = 0; t < 4; ++t) {
            f32x4 z = {0.f, 0.f, 0.f, 0.f};
            acc[t] = __builtin_amdgcn_mfma_f32_16x16x32_bf16(A0, Bf[t][0], z, 0, 0, 0);
            acc[t] = __builtin_amdgcn_mfma_f32_16x16x32_bf16(A1, Bf[t][1], acc[t], 0, 0, 0);
        }

        // C/D layout (cout = t*16+col, row = quad*4+r) -> LDS [row][72].
#pragma unroll
        for (int r = 0; r < 4; ++r) {
            const int row = quad * 4 + r;
#pragma unroll
            for (int t = 0; t < 4; ++t)
                L[row * 72 + t * 16 + col] = f32_to_bf16(acc[t][r]);
        }
        // Writeback: 8 lanes per 128B row; slot broadcast from computing lane.
#pragma unroll
        for (int itr = 0; itr < 2; ++itr) {
            const int row = itr * 8 + (lane >> 3);
            const int chunk = lane & 7;
            const int pos = __shfl(slot, row, 64);
            const u16x8 v = *(const u16x8*)(L + row * 72 + chunk * 8);
            *(u16x8*)(contrib + (size_t)pos * 64 + chunk * 8) = v;
        }
    }
}

// ---------- phase B: streaming segmented sum + fused BN + ReLU ----------
__global__ __launch_bounds__(256) void gather_bn_kernel(
    const unsigned short* __restrict__ contrib, const int* __restrict__ seg,
    const int* __restrict__ cnt,
    const float* __restrict__ gamma, const float* __restrict__ beta,
    const float* __restrict__ mean, const float* __restrict__ var,
    float* __restrict__ out)
{
    const int v = blockIdx.x * 4 + (threadIdx.x >> 6);   // one wave per voxel
    if (v >= N_VOX) return;
    const int lane = threadIdx.x & 63;
    const int half = lane >> 5;        // 0: even rows, 1: odd rows
    const int l = lane & 31;           // uint index (channels 2l, 2l+1)
    const int s = seg[v];
    const int n = cnt[v];

    const unsigned int* p = (const unsigned int*)(contrib + (size_t)s * 64) + l;
    float c0 = 0.f, c1 = 0.f, d0 = 0.f, d1 = 0.f;
    int j = half;
    for (; j + 2 < n; j += 4) {
        const unsigned int u0 = p[(size_t)j * 32];
        const unsigned int u1 = p[(size_t)(j + 2) * 32];
        c0 += bf16_to_f32((unsigned short)u0);
        c1 += bf16_to_f32((unsigned short)(u0 >> 16));
        d0 += bf16_to_f32((unsigned short)u1);
        d1 += bf16_to_f32((unsigned short)(u1 >> 16));
    }
    if (j < n) {
        const unsigned int u0 = p[(size_t)j * 32];
        c0 += bf16_to_f32((unsigned short)u0);
        c1 += bf16_to_f32((unsigned short)(u0 >> 16));
    }
    c0 += d0;
    c1 += d1;
    c0 += __shfl_xor(c0, 32, 64);
    c1 += __shfl_xor(c1, 32, 64);
    if (half == 0) {
        const int ch = 2 * l;
        const float inv0 = rsqrtf(var[ch] + BN_EPS);
        const float inv1 = rsqrtf(var[ch + 1] + BN_EPS);
        const float y0 = (c0 - mean[ch]) * (inv0 * gamma[ch]) + beta[ch];
        const float y1 = (c1 - mean[ch + 1]) * (inv1 * gamma[ch + 1]) + beta[ch + 1];
        float2 r;
        r.x = fmaxf(y0, 0.f);
        r.y = fmaxf(y1, 0.f);
        *(float2*)(out + (size_t)v * 64 + ch) = r;
    }
}

// ---------- fallback (atomic path, used if ws too small) ----------
__global__ __launch_bounds__(256) void prep_small_kernel(
    const float* __restrict__ feats, unsigned short* __restrict__ fb,
    float* __restrict__ out, const float* __restrict__ W,
    unsigned short* __restrict__ Wt)
{
    const int e = blockIdx.x * blockDim.x + threadIdx.x;
    if (e < (N_VOX * CIN) / 4) {
        const int e4 = e * 4;
        const float4 v = *(const float4*)(feats + e4);
        ushort4 b;
        b.x = f32_to_bf16(v.x);
        b.y = f32_to_bf16(v.y);
        b.z = f32_to_bf16(v.z);
        b.w = f32_to_bf16(v.w);
        *(ushort4*)(fb + e4) = b;
        *(float4*)(out + e4) = make_float4(0.f, 0.f, 0.f, 0.f);
    }
    if (e < K_OFF * CIN * COUT) {
        const int k = e / (CIN * COUT);
        const int r = e % (CIN * COUT);
        const int i = r / COUT;
        const int c = r % COUT;
        Wt[k * CIN * COUT + c * CIN + i] = f32_to_bf16(W[e]);
    }
}

__global__ __launch_bounds__(256) void conv_atomic_kernel(
    const unsigned short* __restrict__ fb, const unsigned short* __restrict__ Wt,
    const int* __restrict__ in_idx, const int* __restrict__ out_idx,
    float* __restrict__ out)
{
    const int k = blockIdx.y;
    const int lane = threadIdx.x & 63;
    const int wave = blockIdx.x * 4 + (threadIdx.x >> 6);
    const int col = lane & 15;
    const int quad = lane >> 4;
    bf16x8 Bf[4][2];
    const short* Wk = (const short*)(Wt + k * CIN * COUT);
#pragma unroll
    for (int t = 0; t < 4; ++t) {
        const short* p = Wk + (t * 16 + col) * CIN + quad * 8;
        Bf[t][0] = *(const bf16x8*)(p);
        Bf[t][1] = *(const bf16x8*)(p + 32);
    }
    const int base = k * M_PAIR;
    for (int tile = wave; tile < M_PAIR / 16; tile += 128) {
        const int m0 = base + tile * 16;
        const int rin = in_idx[m0 + col];
        const short* fp = (const short*)fb + (size_t)rin * CIN + quad * 8;
        const bf16x8 A0 = *(const bf16x8*)(fp);
        const bf16x8 A1 = *(const bf16x8*)(fp + 32);
        f32x4 acc[4];
#pragma unroll
        for (int t = 0; t < 4; ++t) {
            f32x4 z = {0.f, 0.f, 0.f, 0.f};
            acc[t] = __builtin_amdgcn_mfma_f32_16x16x32_bf16(A0, Bf[t][0], z, 0, 0, 0);
            acc[t] = __builtin_amdgcn_mfma_f32_16x16x32_bf16(A1, Bf[t][1], acc[t], 0, 0, 0);
        }
        int vo[4];
#pragma unroll
        for (int r = 0; r < 4; ++r) vo[r] = out_idx[m0 + quad * 4 + r];
#pragma unroll
        for (int r = 0; r < 4; ++r) {
            float* op = out + (size_t)vo[r] * COUT + col;
#pragma unroll
            for (int t = 0; t < 4; ++t) atomicAdd(op + t * 16, acc[t][r]);
        }
    }
}

__global__ __launch_bounds__(256) void bn_relu_kernel(
    float* __restrict__ out,
    const float* __restrict__ gamma, const float* __restrict__ beta,
    const float* __restrict__ mean, const float* __restrict__ var)
{
    const int e = blockIdx.x * blockDim.x + threadIdx.x;
    if (e >= N_VOX * COUT) return;
    const int c = e & (COUT - 1);
    const float inv = rsqrtf(var[c] + BN_EPS);
    const float y = (out[e] - mean[c]) * (inv * gamma[c]) + beta[c];
    out[e] = fmaxf(y, 0.f);
}

// ---------- host ----------
extern "C" void kernel_launch(void* const* d_in, const int* in_sizes, int n_in,
                              void* d_out, int out_size, void* d_ws, size_t ws_size,
                              hipStream_t stream) {
    const float* feats = (const float*)d_in[0];
    const float* W     = (const float*)d_in[1];
    const float* gamma = (const float*)d_in[2];
    const float* beta  = (const float*)d_in[3];
    const float* rmean = (const float*)d_in[4];
    const float* rvar  = (const float*)d_in[5];
    const int* in_idx  = (const int*)d_in[6];
    const int* out_idx = (const int*)d_in[7];
    float* out = (float*)d_out;

    char* ws = (char*)d_ws;
    size_t off = 0;
    auto alloc = [&](size_t bytes) {
        size_t p = off;
        off = (off + bytes + 255) & ~(size_t)255;
        return p;
    };
    const size_t o_fb   = alloc((size_t)N_VOX * CIN * 2);
    const size_t o_wt   = alloc((size_t)K_OFF * CIN * COUT * 2);
    const size_t o_cnt  = alloc((size_t)N_VOX * 4);
    const size_t o_tot  = alloc(4);
    const size_t o_seg  = alloc((size_t)N_VOX * 4);
    const size_t o_rank = alloc((size_t)NPAIR * 4);
    const size_t o_ctr  = alloc((size_t)NPAIR * COUT * 2);
    const bool big = (ws_size >= off);       // constant across calls -> graph-safe

    unsigned short* fb  = (unsigned short*)(ws + o_fb);
    unsigned short* Wt  = (unsigned short*)(ws + o_wt);
    int* cnt            = (int*)(ws + o_cnt);
    int* total          = (int*)(ws + o_tot);
    int* seg            = (int*)(ws + o_seg);
    int* rank           = (int*)(ws + o_rank);
    unsigned short* ctr = (unsigned short*)(ws + o_ctr);

    if (big) {
        hipMemsetAsync(cnt, 0, (size_t)N_VOX * 4, stream);
        hipMemsetAsync(total, 0, 4, stream);
        prep_rank_kernel<<<(NPAIR + 255) / 256, 256, 0, stream>>>(
            out_idx, cnt, rank, feats, fb, W, Wt);
        alloc_kernel<<<(N_VOX + 255) / 256, 256, 0, stream>>>(cnt, total, seg);
        conv_scatter_kernel<<<dim3(32, K_OFF), 256, 0, stream>>>(
            fb, Wt, in_idx, out_idx, rank, seg, ctr);
        gather_bn_kernel<<<(N_VOX + 3) / 4, 256, 0, stream>>>(ctr, seg, cnt,
                                                              gamma, beta, rmean, rvar, out);
    } else {
        const int ptot = (N_VOX * CIN) / 4;
        prep_small_kernel<<<(ptot + 255) / 256, 256, 0, stream>>>(feats, fb, out, W, Wt);
        conv_atomic_kernel<<<dim3(32, K_OFF), 256, 0, stream>>>(fb, Wt, in_idx, out_idx, out);
        const int total_e = N_VOX * COUT;
        bn_relu_kernel<<<(total_e + 255) / 256, 256, 0, stream>>>(out, gamma, beta, rmean, rvar);
    }
}